// Round 5
// baseline (561.796 us; speedup 1.0000x reference)
//
#include <hip/hip_runtime.h>

#define BATCH 2048
#define NB 254

typedef float f4u __attribute__((ext_vector_type(4), aligned(4)));

__device__ __forceinline__ float selw(int pd, float w0, float w1, float w2, float w3) {
    return (pd == 0) ? w0 : (pd == 1) ? w1 : (pd == 2) ? w2 : (pd == 3) ? w3 : 0.f;
}

// ---------------- basis ----------------
// TR: input act layout [i][BATCH] (true) or [b][IN] (false).
// BI: output layout [b][IN] (true, fast path) or [i][BATCH] (false, fallback).
template<bool TR, bool BI>
__global__ __launch_bounds__(256) void basis_kernel(
    const float* __restrict__ act, int IN,
    const float* __restrict__ wbp, const float* __restrict__ wsp,
    float2* __restrict__ sjbuf, float4* __restrict__ vbuf)
{
    int idx = blockIdx.x * 256 + threadIdx.x;
    int total = BATCH * IN;
    if (idx >= total) return;
    int i, b;
    if (BI) { b = idx / IN; i = idx - b * IN; }
    else    { i = idx / BATCH; b = idx - i * BATCH; }

    float x = TR ? act[i * BATCH + b] : act[(size_t)b * IN + i];
    float wb = wbp[0], wsc = wsp[0];

    float sil = x / (1.f + __expf(-x));

    const float LO = -0.05f;
    const float INVH = 228.18181818181818f;  // 251/1.1
    float uf = (x - LO) * INVH;
    float fm = floorf(uf);
    float t = uf - fm;
    int M = (int)fm + 3;

    bool valid = (M >= 0) && (M <= 256);
    float wsv = valid ? wsc : 0.f;

    float omt = 1.f - t;
    float t2 = t * t, t3 = t2 * t;
    const float S = 1.f / 6.f;
    float w0 = omt * omt * omt * S * wsv;
    float w1 = (3.f * t3 - 6.f * t2 + 4.f) * S * wsv;
    float w2 = (-3.f * t3 + 3.f * t2 + 3.f * t + 1.f) * S * wsv;
    float w3 = t3 * S * wsv;

    int js = M - 3;
    js = js < 0 ? 0 : js;
    js = js > (NB - 4) ? (NB - 4) : js;
    if (!valid) js = 0;
    int d = js - (M - 3);

    float vp0 = selw(0 + d, w0, w1, w2, w3);
    float vp1 = selw(1 + d, w0, w1, w2, w3);
    float vp2 = selw(2 + d, w0, w1, w2, w3);
    float vp3 = selw(3 + d, w0, w1, w2, w3);

    sjbuf[idx] = make_float2(sil * wb, __int_as_float(js));
    vbuf[idx] = make_float4(vp0, vp1, vp2, vp3);
}

// ---------------- weight transpose (fast path) ----------------
// swT[(i*254 + c)*256 + o] = sw[o][i][c];  O == 256 outputs always here.
__global__ __launch_bounds__(256) void transpose_sw(
    const float* __restrict__ src, float* __restrict__ dst, int IN)
{
    __shared__ float lds[64][68];
    int i  = blockIdx.z;
    int c0 = blockIdx.y * 64;
    int o0 = blockIdx.x * 64;
    int t  = threadIdx.x;
    int q16 = (t & 15) * 4;
    int row = t >> 4;                 // 16 rows per pass

    for (int r = 0; r < 4; r++) {
        int o = row + r * 16;         // o within tile
        int c = c0 + q16;
        const float* sp = src + ((size_t)(o0 + o) * IN + i) * NB + c;
        if (c + 3 < NB) {
            f4u v = *(const f4u*)sp;
            lds[o][q16 + 0] = v[0]; lds[o][q16 + 1] = v[1];
            lds[o][q16 + 2] = v[2]; lds[o][q16 + 3] = v[3];
        } else {
            for (int q = 0; q < 4; q++)
                lds[o][q16 + q] = (c + q < NB) ? sp[q] : 0.f;
        }
    }
    __syncthreads();
    for (int r = 0; r < 4; r++) {
        int cl = row + r * 16;        // c within tile
        int c = c0 + cl;
        if (c < NB) {
            float4 v = make_float4(lds[q16 + 0][cl], lds[q16 + 1][cl],
                                   lds[q16 + 2][cl], lds[q16 + 3][cl]);
            *(float4*)(dst + ((size_t)i * NB + c) * 256 + o0 + q16) = v;
        }
    }
}

// bwT[i][o] = bw[o][i]
__global__ __launch_bounds__(256) void transpose_bw(
    const float* __restrict__ src, float* __restrict__ dst, int IN, int O)
{
    __shared__ float lds[64][65];
    int o0 = blockIdx.x * 64, i0 = blockIdx.y * 64;
    int t = threadIdx.x; int tx = t & 63, ty = t >> 6;
    for (int r = 0; r < 16; r++) {
        int o = ty + r * 4;
        lds[o][tx] = src[(size_t)(o0 + o) * IN + i0 + tx];
    }
    __syncthreads();
    for (int r = 0; r < 16; r++) {
        int irow = ty + r * 4;
        dst[(size_t)(i0 + irow) * O + o0 + tx] = lds[tx][irow];
    }
}

// ---------------- fast accum: lanes own o, j wave-uniform ----------------
// out[b][o] = sum_i( s*bwT[i][o] + sum_k v_k * swT[i][j+k][o] ) + resid[b][o]
// wave = one b, 128 outputs (lane owns o-pair). grid: (BATCH/8, 2), block (64,8).
template<int IN, bool RES>
__global__ __launch_bounds__(512) void accum_T(
    const float2* __restrict__ sjbuf,   // [b][IN]
    const float4* __restrict__ vbuf,    // [b][IN]
    const float* __restrict__ swT,      // [IN][254][256]
    const float* __restrict__ bwT,      // [IN][256]
    const float* __restrict__ resid,    // [b][256]
    float* __restrict__ out)            // [b][256]
{
    int lane = threadIdx.x;
    int w    = threadIdx.y;
    int b    = blockIdx.x * 8 + w;
    int o0   = blockIdx.y * 128 + lane * 2;

    const float2* sj = sjbuf + (size_t)b * IN;
    const float4* vv = vbuf + (size_t)b * IN;

    float a0 = 0.f, a1 = 0.f;

#pragma unroll 4
    for (int i = 0; i < IN; i++) {
        float2 s = sj[i];
        float4 v = vv[i];
        int j = __float_as_int(s.y);
        const float* tp = swT + ((size_t)i * NB + j) * 256 + o0;
        float2 t0 = *(const float2*)(tp);
        float2 t1 = *(const float2*)(tp + 256);
        float2 t2 = *(const float2*)(tp + 512);
        float2 t3 = *(const float2*)(tp + 768);
        float2 bwv = *(const float2*)(bwT + (size_t)i * 256 + o0);
        a0 += s.x * bwv.x + v.x * t0.x + v.y * t1.x + v.z * t2.x + v.w * t3.x;
        a1 += s.x * bwv.y + v.x * t0.y + v.y * t1.y + v.z * t2.y + v.w * t3.y;
    }
    size_t oidx = (size_t)b * 256 + o0;
    float r0 = 0.f, r1 = 0.f;
    if (RES) { float2 rr = *(const float2*)(resid + oidx); r0 = rr.x; r1 = rr.y; }
    *(float2*)(out + oidx) = make_float2(a0 + r0, a1 + r1);
}

// ---------------- fallback gather accum (round-4, [i][b] layouts) ----------------
template<int IN, int OT, bool RES, int IG, int BT>
__global__ __launch_bounds__(BT * IG) void accum_f32(
    const float2* __restrict__ sjbuf, const float4* __restrict__ vbuf,
    const float* __restrict__ bw, const float* __restrict__ sw,
    const float* __restrict__ resid, float* __restrict__ out)
{
    int bx = threadIdx.x;
    int g  = threadIdx.y;
    int b  = blockIdx.y * BT + bx;
    int o0 = blockIdx.x * OT;

    float acc[OT];
#pragma unroll
    for (int k = 0; k < OT; k++) acc[k] = 0.f;

    const size_t ostride = (size_t)IN * NB;
    const int CH = IN / IG;
    const int i0 = g * CH;

    for (int ii = 0; ii < CH; ii++) {
        int i = i0 + ii;
        float2 sj = sjbuf[i * BATCH + b];
        float4 v = vbuf[i * BATCH + b];
        int j = __float_as_int(sj.y);
        float s = sj.x;
        const float* p = sw + (size_t)(o0 * IN + i) * NB + j;
        const float* bq = bw + (size_t)o0 * IN + i;
        f4u wreg[OT];
#pragma unroll
        for (int oo = 0; oo < OT; oo++)
            wreg[oo] = *(const f4u*)(p + (size_t)oo * ostride);
#pragma unroll
        for (int oo = 0; oo < OT; oo++) {
            float bwv = bq[oo * IN];
            acc[oo] += s * bwv + v.x * wreg[oo][0] + v.y * wreg[oo][1] + v.z * wreg[oo][2] + v.w * wreg[oo][3];
        }
    }

    __shared__ float lds[OT * (IG - 1) * BT];
    if (g > 0) {
#pragma unroll
        for (int oo = 0; oo < OT; oo++)
            lds[(oo * (IG - 1) + (g - 1)) * BT + bx] = acc[oo];
    }
    __syncthreads();
    if (g == 0) {
#pragma unroll
        for (int oo = 0; oo < OT; oo++) {
            float a = acc[oo];
            for (int gg = 1; gg < IG; gg++)
                a += lds[(oo * (IG - 1) + (gg - 1)) * BT + bx];
            size_t oidx = (size_t)(o0 + oo) * BATCH + b;
            float r = RES ? resid[oidx] : 0.f;
            out[oidx] = a + r;
        }
    }
}

// ---------------- final layer ----------------
template<bool BI>
__global__ __launch_bounds__(256) void out_kernel(
    const float2* __restrict__ sjbuf, const float4* __restrict__ vbuf,
    const float* __restrict__ bw, const float* __restrict__ sw,
    float* __restrict__ out)
{
    int tid = threadIdx.x;
    int bl = tid >> 6;
    int ig = tid & 63;
    int b = blockIdx.x * 4 + bl;

    float acc = 0.f;
    for (int ii = ig; ii < 256; ii += 64) {
        int idx = BI ? (b * 256 + ii) : (ii * BATCH + b);
        float2 sj = sjbuf[idx];
        float4 v = vbuf[idx];
        int j = __float_as_int(sj.y);
        const float* p = sw + (size_t)ii * NB + j;
        acc += sj.x * bw[ii] + v.x * p[0] + v.y * p[1] + v.z * p[2] + v.w * p[3];
    }
#pragma unroll
    for (int dlt = 32; dlt >= 1; dlt >>= 1) acc += __shfl_down(acc, dlt, 64);
    if (ig == 0) out[b] = acc;
}

extern "C" void kernel_launch(void* const* d_in, const int* in_sizes, int n_in,
                              void* d_out, int out_size, void* d_ws, size_t ws_size,
                              hipStream_t stream)
{
    const float* x   = (const float*)d_in[0];
    const float* bw0 = (const float*)d_in[1];
    const float* sw0 = (const float*)d_in[2];
    const float* wb0 = (const float*)d_in[3];
    const float* ws0 = (const float*)d_in[4];
    const float* bw1 = (const float*)d_in[5];
    const float* sw1 = (const float*)d_in[6];
    const float* wb1 = (const float*)d_in[7];
    const float* ws1 = (const float*)d_in[8];
    const float* bw2 = (const float*)d_in[9];
    const float* sw2 = (const float*)d_in[10];
    const float* wb2 = (const float*)d_in[11];
    const float* ws2 = (const float*)d_in[12];
    const float* bw3 = (const float*)d_in[13];
    const float* sw3 = (const float*)d_in[14];
    const float* wb3 = (const float*)d_in[15];
    const float* ws3 = (const float*)d_in[16];

    char* ws = (char*)d_ws;
    float4* vbuf  = (float4*)(ws);                        // 8 MB
    float2* sjbuf = (float2*)(ws + 8  * 1024 * 1024);     // 4 MB
    float*  hA    = (float*)(ws + 12 * 1024 * 1024);      // 2 MB
    float*  hB    = (float*)(ws + 14 * 1024 * 1024);      // 2 MB

    // fast-path transposed-weight buffers
    const size_t SWT0_OFF = 16777216u;                    // 16 MiB
    const size_t SWT0_SZ  = (size_t)64  * NB * 256 * 4;   // 16,646,144
    const size_t SWT1_OFF = SWT0_OFF + SWT0_SZ;
    const size_t SWT1_SZ  = (size_t)256 * NB * 256 * 4;   // 66,584,576
    const size_t SWT2_OFF = SWT1_OFF + SWT1_SZ;
    const size_t BWT0_OFF = SWT2_OFF + SWT1_SZ;
    const size_t BWT1_OFF = BWT0_OFF + 65536u;
    const size_t BWT2_OFF = BWT1_OFF + 262144u;
    const size_t NEED     = BWT2_OFF + 262144u;           // ~159.4 MiB

    float* swT0 = (float*)(ws + SWT0_OFF);
    float* swT1 = (float*)(ws + SWT1_OFF);
    float* swT2 = (float*)(ws + SWT2_OFF);
    float* bwT0 = (float*)(ws + BWT0_OFF);
    float* bwT1 = (float*)(ws + BWT1_OFF);
    float* bwT2 = (float*)(ws + BWT2_OFF);

    float* out = (float*)d_out;
    bool fast = (ws_size >= NEED);

    if (fast) {
        transpose_sw<<<dim3(4, 4, 64),  256, 0, stream>>>(sw0, swT0, 64);
        transpose_sw<<<dim3(4, 4, 256), 256, 0, stream>>>(sw1, swT1, 256);
        transpose_sw<<<dim3(4, 4, 256), 256, 0, stream>>>(sw2, swT2, 256);
        transpose_bw<<<dim3(4, 1), 256, 0, stream>>>(bw0, bwT0, 64, 256);
        transpose_bw<<<dim3(4, 4), 256, 0, stream>>>(bw1, bwT1, 256, 256);
        transpose_bw<<<dim3(4, 4), 256, 0, stream>>>(bw2, bwT2, 256, 256);

        dim3 ablk(64, 8);
        dim3 agrd(BATCH / 8, 2);

        basis_kernel<false, true><<<BATCH * 64 / 256, 256, 0, stream>>>(x, 64, wb0, ws0, sjbuf, vbuf);
        accum_T<64, false><<<agrd, ablk, 0, stream>>>(sjbuf, vbuf, swT0, bwT0, nullptr, hA);

        basis_kernel<false, true><<<BATCH * 256 / 256, 256, 0, stream>>>(hA, 256, wb1, ws1, sjbuf, vbuf);
        accum_T<256, true><<<agrd, ablk, 0, stream>>>(sjbuf, vbuf, swT1, bwT1, hA, hB);

        basis_kernel<false, true><<<BATCH * 256 / 256, 256, 0, stream>>>(hB, 256, wb2, ws2, sjbuf, vbuf);
        accum_T<256, true><<<agrd, ablk, 0, stream>>>(sjbuf, vbuf, swT2, bwT2, hB, hA);

        basis_kernel<false, true><<<BATCH * 256 / 256, 256, 0, stream>>>(hA, 256, wb3, ws3, sjbuf, vbuf);
        out_kernel<true><<<BATCH / 4, 256, 0, stream>>>(sjbuf, vbuf, bw3, sw3, out);
    } else {
        dim3 ablk(64, 8);
        dim3 agrd(32, 32);
        basis_kernel<false, false><<<BATCH * 64 / 256, 256, 0, stream>>>(x, 64, wb0, ws0, sjbuf, vbuf);
        accum_f32<64, 8, false, 8, 64><<<agrd, ablk, 0, stream>>>(sjbuf, vbuf, bw0, sw0, nullptr, hA);

        basis_kernel<true, false><<<BATCH * 256 / 256, 256, 0, stream>>>(hA, 256, wb1, ws1, sjbuf, vbuf);
        accum_f32<256, 8, true, 8, 64><<<agrd, ablk, 0, stream>>>(sjbuf, vbuf, bw1, sw1, hA, hB);

        basis_kernel<true, false><<<BATCH * 256 / 256, 256, 0, stream>>>(hB, 256, wb2, ws2, sjbuf, vbuf);
        accum_f32<256, 8, true, 8, 64><<<agrd, ablk, 0, stream>>>(sjbuf, vbuf, bw2, sw2, hB, hA);

        basis_kernel<true, false><<<BATCH * 256 / 256, 256, 0, stream>>>(hA, 256, wb3, ws3, sjbuf, vbuf);
        out_kernel<false><<<BATCH / 4, 256, 0, stream>>>(sjbuf, vbuf, bw3, sw3, out);
    }
}

// Round 6
// 285.123 us; speedup vs baseline: 1.9704x; 1.9704x over previous
//
#include <hip/hip_runtime.h>

#define BATCH 2048
#define NB 254

typedef float f4u __attribute__((ext_vector_type(4), aligned(4)));

__device__ __forceinline__ float selw(int pd, float w0, float w1, float w2, float w3) {
    return (pd == 0) ? w0 : (pd == 1) ? w1 : (pd == 2) ? w2 : (pd == 3) ? w3 : 0.f;
}

// Per (b,i): silu(x)*wb, 4 spline tap weights *ws (shifted into clamped window), window start j.
// Invalid (x outside grid) -> js = -1 (accum skips the gather entirely; spline contributes 0).
// TR: input activation layout. false: act[b][IN] (layer-0 x). true: act[i][BATCH] (transposed hidden).
template<bool TR>
__global__ __launch_bounds__(256) void basis_kernel(
    const float* __restrict__ act, int IN,
    const float* __restrict__ wbp, const float* __restrict__ wsp,
    float2* __restrict__ sjbuf, float4* __restrict__ vbuf)
{
    int idx = blockIdx.x * 256 + threadIdx.x;
    int total = BATCH * IN;
    if (idx >= total) return;
    int i = idx / BATCH;
    int b = idx - i * BATCH;

    float x = TR ? act[idx] : act[(size_t)b * IN + i];
    float wb = wbp[0], wsc = wsp[0];

    float sil = x / (1.f + __expf(-x));

    const float LO = -0.05f;
    const float INVH = 228.18181818181818f;  // 251/1.1
    float uf = (x - LO) * INVH;
    float fm = floorf(uf);
    float t = uf - fm;
    int M = (int)fm + 3;     // grid interval index: x in [GRID[M], GRID[M+1])

    bool valid = (M >= 0) && (M <= 256);

    float omt = 1.f - t;
    float t2 = t * t, t3 = t2 * t;
    const float S = 1.f / 6.f;
    float w0 = omt * omt * omt * S * wsc;
    float w1 = (3.f * t3 - 6.f * t2 + 4.f) * S * wsc;
    float w2 = (-3.f * t3 + 3.f * t2 + 3.f * t + 1.f) * S * wsc;
    float w3 = t3 * S * wsc;

    int js = M - 3;
    js = js < 0 ? 0 : js;
    js = js > (NB - 4) ? (NB - 4) : js;
    int d = js - (M - 3);    // shift of taps inside the clamped window, in [-3,3]

    float vp0 = selw(0 + d, w0, w1, w2, w3);
    float vp1 = selw(1 + d, w0, w1, w2, w3);
    float vp2 = selw(2 + d, w0, w1, w2, w3);
    float vp3 = selw(3 + d, w0, w1, w2, w3);

    if (!valid) js = -1;     // signal: no spline contribution, skip gathers

    sjbuf[idx] = make_float2(sil * wb, __int_as_float(js));
    vbuf[idx] = make_float4(vp0, vp1, vp2, vp3);
}

// out[o][b] = sum_i ( s[b,i]*bw[o,i] + [j>=0] dot(v4[b,i], sw[o,i,j..j+3]) ) (+resid[o][b])
// Block: BT b-lanes (x) * IG i-groups (y). Output/residual in transposed [o][BATCH] layout.
// Spline gathers are exec-mask predicated on j >= 0 (~60% of lanes active on hidden layers).
template<int IN, int OT, bool RES, int IG, int BT>
__global__ __launch_bounds__(BT * IG) void accum_f32(
    const float2* __restrict__ sjbuf, const float4* __restrict__ vbuf,
    const float* __restrict__ bw, const float* __restrict__ sw,
    const float* __restrict__ resid, float* __restrict__ out)
{
    int bx = threadIdx.x;              // b lane within tile
    int g  = threadIdx.y;              // i-group
    int b  = blockIdx.y * BT + bx;
    int o0 = blockIdx.x * OT;

    float acc[OT];
#pragma unroll
    for (int k = 0; k < OT; k++) acc[k] = 0.f;

    const size_t ostride = (size_t)IN * NB;
    const int CH = IN / IG;
    const int i0 = g * CH;

    for (int ii = 0; ii < CH; ii++) {
        int i = i0 + ii;
        float2 sj = sjbuf[i * BATCH + b];
        int j = __float_as_int(sj.y);
        float s = sj.x;
        const float* bq = bw + (size_t)o0 * IN + i;   // scalar-computable (SGPR path)

        // base path: always, all lanes
#pragma unroll
        for (int oo = 0; oo < OT; oo++)
            acc[oo] += s * bq[oo * IN];

        // spline path: only lanes with in-grid x issue the 8 gathers
        if (j >= 0) {
            float4 v = vbuf[i * BATCH + b];
            const float* p = sw + (size_t)(o0 * IN + i) * NB + j;
            f4u wreg[OT];
#pragma unroll
            for (int oo = 0; oo < OT; oo++)
                wreg[oo] = *(const f4u*)(p + (size_t)oo * ostride);
#pragma unroll
            for (int oo = 0; oo < OT; oo++)
                acc[oo] += v.x * wreg[oo][0] + v.y * wreg[oo][1] + v.z * wreg[oo][2] + v.w * wreg[oo][3];
        }
    }

    // LDS reduce across i-groups. Layout [oo][g-1][bx]: lane-stride 1, conflict-free.
    __shared__ float lds[OT * (IG - 1) * BT];
    if (g > 0) {
#pragma unroll
        for (int oo = 0; oo < OT; oo++)
            lds[(oo * (IG - 1) + (g - 1)) * BT + bx] = acc[oo];
    }
    __syncthreads();
    if (g == 0) {
#pragma unroll
        for (int oo = 0; oo < OT; oo++) {
            float a = acc[oo];
            for (int gg = 1; gg < IG; gg++)
                a += lds[(oo * (IG - 1) + (gg - 1)) * BT + bx];
            size_t oidx = (size_t)(o0 + oo) * BATCH + b;
            float r = RES ? resid[oidx] : 0.f;
            out[oidx] = a + r;
        }
    }
}

// Final layer: out=1, f32 weights. 64 lanes per batch row, shuffle-reduce.
__global__ __launch_bounds__(256) void out_kernel(
    const float2* __restrict__ sjbuf, const float4* __restrict__ vbuf,
    const float* __restrict__ bw, const float* __restrict__ sw,
    float* __restrict__ out)
{
    int tid = threadIdx.x;
    int bl = tid >> 6;
    int ig = tid & 63;
    int b = blockIdx.x * 4 + bl;

    float acc = 0.f;
    for (int ii = ig; ii < 256; ii += 64) {
        float2 sj = sjbuf[ii * BATCH + b];
        int j = __float_as_int(sj.y);
        acc += sj.x * bw[ii];
        if (j >= 0) {
            float4 v = vbuf[ii * BATCH + b];
            const float* p = sw + (size_t)ii * NB + j;
            acc += v.x * p[0] + v.y * p[1] + v.z * p[2] + v.w * p[3];
        }
    }
#pragma unroll
    for (int dlt = 32; dlt >= 1; dlt >>= 1) acc += __shfl_down(acc, dlt, 64);
    if (ig == 0) out[b] = acc;
}

extern "C" void kernel_launch(void* const* d_in, const int* in_sizes, int n_in,
                              void* d_out, int out_size, void* d_ws, size_t ws_size,
                              hipStream_t stream)
{
    const float* x   = (const float*)d_in[0];
    const float* bw0 = (const float*)d_in[1];
    const float* sw0 = (const float*)d_in[2];
    const float* wb0 = (const float*)d_in[3];
    const float* ws0 = (const float*)d_in[4];
    const float* bw1 = (const float*)d_in[5];
    const float* sw1 = (const float*)d_in[6];
    const float* wb1 = (const float*)d_in[7];
    const float* ws1 = (const float*)d_in[8];
    const float* bw2 = (const float*)d_in[9];
    const float* sw2 = (const float*)d_in[10];
    const float* wb2 = (const float*)d_in[11];
    const float* ws2 = (const float*)d_in[12];
    const float* bw3 = (const float*)d_in[13];
    const float* sw3 = (const float*)d_in[14];
    const float* wb3 = (const float*)d_in[15];
    const float* ws3 = (const float*)d_in[16];

    char* ws = (char*)d_ws;
    float4* vbuf  = (float4*)(ws);                        // 8 MB
    float2* sjbuf = (float2*)(ws + 8  * 1024 * 1024);     // 4 MB
    float*  hA    = (float*)(ws + 12 * 1024 * 1024);      // 2 MB  ([o][b] layout)
    float*  hB    = (float*)(ws + 14 * 1024 * 1024);      // 2 MB  ([o][b] layout)

    float* out = (float*)d_out;

    dim3 ablk(64, 8);     // BT=64 (one wave per i-group slice), IG=8 -> 512 threads
    dim3 agrd(32, 32);    // 32 o-tiles x 32 b-tiles of 64 -> 1024 blocks (4/CU)

    // Layer 0: 64 -> 256 (x is [b][64], all in-grid)
    basis_kernel<false><<<(BATCH * 64 + 255) / 256, 256, 0, stream>>>(x, 64, wb0, ws0, sjbuf, vbuf);
    accum_f32<64, 8, false, 8, 64><<<agrd, ablk, 0, stream>>>(sjbuf, vbuf, bw0, sw0, nullptr, hA);

    // Layer 1: 256 -> 256, residual (hA is [o][b] == [i][b] for next layer)
    basis_kernel<true><<<(BATCH * 256 + 255) / 256, 256, 0, stream>>>(hA, 256, wb1, ws1, sjbuf, vbuf);
    accum_f32<256, 8, true, 8, 64><<<agrd, ablk, 0, stream>>>(sjbuf, vbuf, bw1, sw1, hA, hB);

    // Layer 2: 256 -> 256, residual
    basis_kernel<true><<<(BATCH * 256 + 255) / 256, 256, 0, stream>>>(hB, 256, wb2, ws2, sjbuf, vbuf);
    accum_f32<256, 8, true, 8, 64><<<agrd, ablk, 0, stream>>>(sjbuf, vbuf, bw2, sw2, hB, hA);

    // Layer 3: 256 -> 1
    basis_kernel<true><<<(BATCH * 256 + 255) / 256, 256, 0, stream>>>(hA, 256, wb3, ws3, sjbuf, vbuf);
    out_kernel<<<BATCH / 4, 256, 0, stream>>>(sjbuf, vbuf, bw3, sw3, out);
}